// Round 14
// baseline (4643.591 us; speedup 1.0000x reference)
//
#include <hip/hip_runtime.h>

// ---------------- problem constants ----------------
#define T_STEPS 512
#define BATCH_N 256
#define IDIM    128
#define NDIM    1024
#define ODIM    10

// 256 WGs = 16 batch-groups (16 rows) x 16 col-slices (64 cols), 4 waves.
// R14: per-wave decoupled protocol. Each wave gathers ITS OWN K-quarter
// (16 rows x 512B, coalesced) into a PRIVATE LDS tile -> no cross-wave LDS
// dependency -> the only barrier left is bar2 (K-reduction, parity-buffered).
// Per-wave flags (64/group): each wave polls the 256B flag line itself,
// publishes its 4 y-values, drains ONLY those stores, flags, prefetches.
#define THREADS 256
#define GAIN 0.03125f

// ---------------- workspace layout (bytes) ----------------
#define YBUF_OFF    (33554432ull)                 // bf16 y [2][16][16][1024]
#define YBUF_HALF   (524288ull)
#define YHALF_EL    (262144u)
#define FLG_OFF     (YBUF_OFF + 2*YBUF_HALF)
#define FLG_BYTES   (4096ull)                     // u32 [16 groups][64 waves]
#define XT_OFF      (FLG_OFF + FLG_BYTES)
#define XT_BYTES    (1048576ull)
#define WS_NEED     (XT_OFF + XT_BYTES)

typedef short    s16x8 __attribute__((ext_vector_type(8)));
typedef float    f32x4 __attribute__((ext_vector_type(4)));
typedef unsigned u32x4 __attribute__((ext_vector_type(4)));

__device__ __forceinline__ unsigned short f2bf(float f) {
  unsigned u = __builtin_bit_cast(unsigned, f);
  u += 0x7fffu + ((u >> 16) & 1u);               // RTNE
  return (unsigned short)(u >> 16);
}

// ---------------- batch fp32 -> bf16 prepass ----------------
__global__ void horn_convert(const float* __restrict__ src, unsigned short* __restrict__ dst) {
  size_t gid = (size_t)blockIdx.x * 256 + threadIdx.x;
  const f32x4* s4 = reinterpret_cast<const f32x4*>(src) + gid * 2;
  f32x4 a = s4[0], b = s4[1];
  u32x4 o;
  o[0] = (unsigned)f2bf(a[0]) | ((unsigned)f2bf(a[1]) << 16);
  o[1] = (unsigned)f2bf(a[2]) | ((unsigned)f2bf(a[3]) << 16);
  o[2] = (unsigned)f2bf(b[0]) | ((unsigned)f2bf(b[1]) << 16);
  o[3] = (unsigned)f2bf(b[2]) | ((unsigned)f2bf(b[3]) << 16);
  reinterpret_cast<u32x4*>(dst)[gid] = o;
}

// ---------------- persistent recurrent kernel ----------------
// LDS: ylds[4 waves][8KB private K-quarter tile] + red[2 parity][16][64] f32x4
__launch_bounds__(THREADS, 1)
__global__ void horn_persistent(const unsigned short* __restrict__ batchbf,
                                const float* __restrict__ i2h_w,
                                const float* __restrict__ i2h_b,
                                const float* __restrict__ h2h_w,
                                const float* __restrict__ h2h_b,
                                unsigned short* ybuf,     // bf16 [2][16][16][1024]
                                unsigned int*  flags,     // u32 [16][64]
                                float* xT)                // [256][1024] fp32
{
  __shared__ char  ylds[32768];                    // wave wv: [wv*8192, +8192)
  __shared__ f32x4 red[2][16][64];                 // [parity][wv*4+ct][lane]

  const int tid  = threadIdx.x;
  const int lane = tid & 63;
  const int wv   = tid >> 6;          // wave 0..3: K-quarter wv, owned ct = wv
  const int blk  = blockIdx.x;
  const int ig   = blk & 15;          // batch group (16 rows)
  const int jg   = blk >> 4;          // col-slice 0..15 (64 cols)
  const int l15  = lane & 15;
  const int kb   = lane >> 4;
  const int jc   = jg * 64 + wv * 16 + l15;        // owned output column

  // ---- W fragments: 4 ct x 8 kc (K-quarter wv), xGAIN = 128 VGPRs ----
  s16x8 wfrag[4][8];
  #pragma unroll
  for (int ct = 0; ct < 4; ++ct) {
    #pragma unroll
    for (int kc = 0; kc < 8; ++kc) {
      const float* gp = h2h_w + (size_t)(jg * 64 + ct * 16 + l15) * NDIM
                        + wv * 256 + kc * 32 + kb * 8;
      f32x4 a = *reinterpret_cast<const f32x4*>(gp);
      f32x4 b = *reinterpret_cast<const f32x4*>(gp + 4);
      s16x8 v;
      v[0] = (short)f2bf(a[0]*GAIN); v[1] = (short)f2bf(a[1]*GAIN);
      v[2] = (short)f2bf(a[2]*GAIN); v[3] = (short)f2bf(a[3]*GAIN);
      v[4] = (short)f2bf(b[0]*GAIN); v[5] = (short)f2bf(b[1]*GAIN);
      v[6] = (short)f2bf(b[2]*GAIN); v[7] = (short)f2bf(b[3]*GAIN);
      wfrag[ct][kc] = v;
    }
  }
  // ---- i2h B-frags + fused bias ----
  s16x8 i2hf[4];
  #pragma unroll
  for (int kc = 0; kc < 4; ++kc) {
    const float* gp = i2h_w + (size_t)jc * IDIM + kc * 32 + kb * 8;
    s16x8 v;
    #pragma unroll
    for (int e = 0; e < 8; ++e) v[e] = (short)f2bf(gp[e]);
    i2hf[kc] = v;
  }
  const float bias = i2h_b[jc] + GAIN * h2h_b[jc];

  // ---- per-lane pointers ----
  // gather: wave wv K-quarter; load i covers rows {2i, 2i+1}; lane: row=2i+(lane>>5),
  // within-quarter byte = (lane&31)*16. addr = base + row*2048 + wv*512 + (lane&31)*16
  const char* gb0 = (const char*)ybuf + (size_t)ig * 32768
                    + (size_t)(lane >> 5) * 2048 + wv * 512 + (lane & 31) * 16;
  unsigned short* pub0 = ybuf + (size_t)(ig * 16 + kb * 4) * 1024 + jc;
  const unsigned* fpoll = flags + ig * 64 + lane;
  unsigned* fstore = flags + ig * 64 + jg * 4 + wv;
  const char* bb = (const char*)batchbf;
  const size_t boff_lane = (size_t)(ig * 16 + l15) * 256 + kb * 16;  // + t*65536

  float xs[4] = {0,0,0,0}, ys[4] = {0,0,0,0};
  u32x4 pf0, pf1, pf2, pf3;                        // batch prefetch regs
  u32x4 gy0, gy1, gy2, gy3, gy4, gy5, gy6, gy7;    // y gather regs

  #define PREFETCH(T) { const char* bp_ = bb + (size_t)(T) * 65536 + boff_lane; \
    asm volatile( \
      "global_load_dwordx4 %0, %4, off offset:0\n\t"  \
      "global_load_dwordx4 %1, %4, off offset:64\n\t" \
      "global_load_dwordx4 %2, %4, off offset:128\n\t"\
      "global_load_dwordx4 %3, %4, off offset:192"    \
      : "=&v"(pf0), "=&v"(pf1), "=&v"(pf2), "=&v"(pf3) : "v"(bp_) : "memory"); }

  #define UPHASE(uacc) { \
    uacc = __builtin_amdgcn_mfma_f32_16x16x32_bf16(__builtin_bit_cast(s16x8, pf0), i2hf[0], uacc, 0, 0, 0); \
    uacc = __builtin_amdgcn_mfma_f32_16x16x32_bf16(__builtin_bit_cast(s16x8, pf1), i2hf[1], uacc, 0, 0, 0); \
    uacc = __builtin_amdgcn_mfma_f32_16x16x32_bf16(__builtin_bit_cast(s16x8, pf2), i2hf[2], uacc, 0, 0, 0); \
    uacc = __builtin_amdgcn_mfma_f32_16x16x32_bf16(__builtin_bit_cast(s16x8, pf3), i2hf[3], uacc, 0, 0, 0); }

  #define UPD4(z) \
    unsigned yw0, yw1, yw2, yw3; { float z_, e_, th_, yn_; \
    z_ = z[0]; e_ = __expf(z_ + z_); th_ = fmaf(-2.0f, __builtin_amdgcn_rcpf(e_ + 1.0f), 1.0f); \
    yn_ = ys[0] + 0.1f*(th_ - xs[0] - 0.2f*ys[0]); xs[0] += 0.1f*yn_; ys[0] = yn_; yw0 = f2bf(yn_); \
    z_ = z[1]; e_ = __expf(z_ + z_); th_ = fmaf(-2.0f, __builtin_amdgcn_rcpf(e_ + 1.0f), 1.0f); \
    yn_ = ys[1] + 0.1f*(th_ - xs[1] - 0.2f*ys[1]); xs[1] += 0.1f*yn_; ys[1] = yn_; yw1 = f2bf(yn_); \
    z_ = z[2]; e_ = __expf(z_ + z_); th_ = fmaf(-2.0f, __builtin_amdgcn_rcpf(e_ + 1.0f), 1.0f); \
    yn_ = ys[2] + 0.1f*(th_ - xs[2] - 0.2f*ys[2]); xs[2] += 0.1f*yn_; ys[2] = yn_; yw2 = f2bf(yn_); \
    z_ = z[3]; e_ = __expf(z_ + z_); th_ = fmaf(-2.0f, __builtin_amdgcn_rcpf(e_ + 1.0f), 1.0f); \
    yn_ = ys[3] + 0.1f*(th_ - xs[3] - 0.2f*ys[3]); xs[3] += 0.1f*yn_; ys[3] = yn_; yw3 = f2bf(yn_); }

  #define PUBLISH(PN) { \
    unsigned short* b0_ = pub0 + (size_t)(PN) * YHALF_EL; \
    unsigned short* b1_ = b0_ + 2 * NDIM; \
    asm volatile( \
      "global_store_short %4, %0, off offset:0    sc0 sc1\n\t" \
      "global_store_short %4, %1, off offset:2048 sc0 sc1\n\t" \
      "global_store_short %5, %2, off offset:0    sc0 sc1\n\t" \
      "global_store_short %5, %3, off offset:2048 sc0 sc1" \
      :: "v"(yw0), "v"(yw1), "v"(yw2), "v"(yw3), "v"(b0_), "v"(b1_) : "memory"); }

  #define SETFLAG(V) { unsigned nv_ = (unsigned)(V); \
    asm volatile("global_store_dword %0, %1, off sc0 sc1" :: "v"(fstore), "v"(nv_) : "memory"); }

  // ---- prologue: step t=0 (y_0 = 0 -> u-phase only) ----
  PREFETCH(0)
  asm volatile("s_waitcnt vmcnt(0)" ::: "memory");
  __builtin_amdgcn_sched_barrier(0);
  {
    f32x4 uacc = {bias, bias, bias, bias};
    UPHASE(uacc)
    UPD4(uacc)
    PUBLISH(1)                                     // y_1 -> parity 1
    asm volatile("s_waitcnt vmcnt(0)" ::: "memory");
    SETFLAG(1)
    PREFETCH(1)
  }

  #pragma unroll 1
  for (int t = 1; t < T_STEPS; ++t) {
    const int p = t & 1, pn = p ^ 1;

    // ---- per-wave poll: all 64 producer-waves of this group flagged >= t ----
    // (embedded vmcnt(0) also drains last step's flag store + batch prefetch)
    while (true) {
      unsigned fv;
      asm volatile("global_load_dword %0, %1, off sc0 sc1\n\ts_waitcnt vmcnt(0)"
                   : "=v"(fv) : "v"(fpoll) : "memory");
      if (__all((int)fv >= t)) break;
      __builtin_amdgcn_s_sleep(1);
    }
    __builtin_amdgcn_sched_barrier(0);

    // ---- issue own K-quarter gather: 8 loads, 2 contiguous rows each ----
    {
      const char* g0 = gb0 + (size_t)p * YBUF_HALF;
      asm volatile(
        "global_load_dwordx4 %0, %8, off sc0 sc1\n\t"
        "global_load_dwordx4 %1, %9, off sc0 sc1\n\t"
        "global_load_dwordx4 %2, %10, off sc0 sc1\n\t"
        "global_load_dwordx4 %3, %11, off sc0 sc1\n\t"
        "global_load_dwordx4 %4, %12, off sc0 sc1\n\t"
        "global_load_dwordx4 %5, %13, off sc0 sc1\n\t"
        "global_load_dwordx4 %6, %14, off sc0 sc1\n\t"
        "global_load_dwordx4 %7, %15, off sc0 sc1"
        : "=&v"(gy0), "=&v"(gy1), "=&v"(gy2), "=&v"(gy3),
          "=&v"(gy4), "=&v"(gy5), "=&v"(gy6), "=&v"(gy7)
        : "v"(g0), "v"(g0 + 4096), "v"(g0 + 8192), "v"(g0 + 12288),
          "v"(g0 + 16384), "v"(g0 + 20480), "v"(g0 + 24576), "v"(g0 + 28672)
        : "memory");
    }

    // ---- u-phase under the gather shadow (pf drained by poll's vmcnt(0)) ----
    f32x4 uacc = {bias, bias, bias, bias};
    UPHASE(uacc)

    asm volatile("s_waitcnt vmcnt(0)" ::: "memory");
    __builtin_amdgcn_sched_barrier(0);

    // ---- stage to private LDS tile (rows 512B, XOR-swizzled) ----
    {
      char* base = ylds + wv * 8192;
      int h = lane >> 5, c16 = (lane & 31) << 4;
      #define STG(i, vr) { int row_ = 2 * (i) + h; \
        *reinterpret_cast<u32x4*>(base + row_ * 512 + (c16 ^ ((row_ & 7) << 4))) = vr; }
      STG(0, gy0) STG(1, gy1) STG(2, gy2) STG(3, gy3)
      STG(4, gy4) STG(5, gy5) STG(6, gy6) STG(7, gy7)
      #undef STG
    }
    asm volatile("s_waitcnt lgkmcnt(0)" ::: "memory");
    __builtin_amdgcn_sched_barrier(0);

    // ---- rec partials from own tile: 4 ct x 8 kc MFMAs ----
    f32x4 c0 = {0,0,0,0}, c1 = {0,0,0,0}, c2 = {0,0,0,0}, c3 = {0,0,0,0};
    {
      const char* base = ylds + wv * 8192 + l15 * 512;
      const int swz = (l15 & 7) << 4;
      #pragma unroll
      for (int kc = 0; kc < 8; ++kc) {
        s16x8 a = *reinterpret_cast<const s16x8*>(base + ((kc * 64 + kb * 16) ^ swz));
        c0 = __builtin_amdgcn_mfma_f32_16x16x32_bf16(a, wfrag[0][kc], c0, 0, 0, 0);
        c1 = __builtin_amdgcn_mfma_f32_16x16x32_bf16(a, wfrag[1][kc], c1, 0, 0, 0);
        c2 = __builtin_amdgcn_mfma_f32_16x16x32_bf16(a, wfrag[2][kc], c2, 0, 0, 0);
        c3 = __builtin_amdgcn_mfma_f32_16x16x32_bf16(a, wfrag[3][kc], c3, 0, 0, 0);
      }
    }

    // ---- cross-wave K-reduction (parity double-buffered) ----
    red[p][wv * 4 + 0][lane] = c0;
    red[p][wv * 4 + 1][lane] = c1;
    red[p][wv * 4 + 2][lane] = c2;
    red[p][wv * 4 + 3][lane] = c3;
    __syncthreads();                               // the ONE barrier per step
    f32x4 z = uacc;
    z += red[p][0 * 4 + wv][lane];
    z += red[p][1 * 4 + wv][lane];
    z += red[p][2 * 4 + wv][lane];
    z += red[p][3 * 4 + wv][lane];

    // ---- update, publish, counted drain (stores only), flag, prefetch ----
    UPD4(z)
    PUBLISH(pn)
    asm volatile("s_waitcnt vmcnt(0)" ::: "memory");   // only the 4 stores in flight
    SETFLAG(t + 1)
    const int tn = (t + 1 < T_STEPS) ? (t + 1) : t;
    PREFETCH(tn)
  }

  #undef PREFETCH
  #undef UPHASE
  #undef UPD4
  #undef PUBLISH
  #undef SETFLAG

  asm volatile("s_waitcnt vmcnt(0)" ::: "memory");

  // ---- write x_T (owned column, 4 rows) ----
  #pragma unroll
  for (int q = 0; q < 4; ++q) {
    int row = ig * 16 + kb * 4 + q;
    xT[(size_t)row * NDIM + jc] = xs[q];
  }
}

// ---------------- final readout: out = x_T @ h2o^T + b ----------------
__global__ void horn_out(const float* __restrict__ xT, const float* __restrict__ h2o_w,
                         const float* __restrict__ h2o_b, float* __restrict__ out) {
  int b = blockIdx.x;
  int lane = threadIdx.x;                  // 64 threads
  float p[ODIM];
  #pragma unroll
  for (int o = 0; o < ODIM; ++o) p[o] = 0.f;
  for (int it = 0; it < NDIM / 64; ++it) {
    int n = it * 64 + lane;
    float xv = xT[(size_t)b * NDIM + n];
    #pragma unroll
    for (int o = 0; o < ODIM; ++o) p[o] += xv * h2o_w[o * NDIM + n];
  }
  #pragma unroll
  for (int o = 0; o < ODIM; ++o) {
    float v = p[o];
    #pragma unroll
    for (int off = 32; off >= 1; off >>= 1) v += __shfl_down(v, off, 64);
    if (lane == 0) out[b * ODIM + o] = v + h2o_b[o];
  }
}

__global__ void horn_fail(float* out) {    // loud sentinel if ws too small
  int i = blockIdx.x * 256 + threadIdx.x;
  if (i < BATCH_N * ODIM) out[i] = 12345.0f;
}

extern "C" void kernel_launch(void* const* d_in, const int* in_sizes, int n_in,
                              void* d_out, int out_size, void* d_ws, size_t ws_size,
                              hipStream_t stream) {
  const float* batch = (const float*)d_in[0];
  const float* i2h_w = (const float*)d_in[1];
  const float* i2h_b = (const float*)d_in[2];
  const float* h2h_w = (const float*)d_in[3];
  const float* h2h_b = (const float*)d_in[4];
  const float* h2o_w = (const float*)d_in[5];
  const float* h2o_b = (const float*)d_in[6];
  float* out = (float*)d_out;
  char* ws = (char*)d_ws;

  if (ws_size < WS_NEED) {
    horn_fail<<<16, 256, 0, stream>>>(out);
    return;
  }

  hipMemsetAsync(ws + FLG_OFF, 0, FLG_BYTES, stream);    // flags = 0

  horn_convert<<<8192, 256, 0, stream>>>(batch, (unsigned short*)(ws + 0));

  horn_persistent<<<256, THREADS, 0, stream>>>(
      (const unsigned short*)(ws + 0), i2h_w, i2h_b, h2h_w, h2h_b,
      (unsigned short*)(ws + YBUF_OFF), (unsigned int*)(ws + FLG_OFF),
      (float*)(ws + XT_OFF));

  horn_out<<<BATCH_N, 64, 0, stream>>>((const float*)(ws + XT_OFF), h2o_w, h2o_b, out);
}

// Round 16
// 3443.363 us; speedup vs baseline: 1.3486x; 1.3486x over previous
//
#include <hip/hip_runtime.h>

// ---------------- problem constants ----------------
#define T_STEPS 512
#define BATCH_N 256
#define IDIM    128
#define NDIM    1024
#define ODIM    10

// 256 WGs = 16 batch-groups (16 rows) x 16 col-slices (64 cols), 4 waves.
// R16 = R15 (wv0-only poll + private per-wave K-quarter gather + per-wave
// flags + counted vmcnt(4) drain) with the R15 NaN bug fixed: waves 1-3
// consumed asm-prefetched batch regs with no vmcnt wait (barP does NOT
// drain asm-issued loads). Fix: vmcnt(8) + sched_barrier after gather
// issue -> retires the 5 oldest (4 prefetch loads + flag store) exactly.
#define THREADS 256
#define GAIN 0.03125f

// ---------------- workspace layout (bytes) ----------------
#define YBUF_OFF    (33554432ull)                 // bf16 y [2][16][16][1024]
#define YBUF_HALF   (524288ull)
#define YHALF_EL    (262144u)
#define FLG_OFF     (YBUF_OFF + 2*YBUF_HALF)
#define FLG_BYTES   (4096ull)                     // u32 [16 groups][64 waves]
#define XT_OFF      (FLG_OFF + FLG_BYTES)
#define XT_BYTES    (1048576ull)
#define WS_NEED     (XT_OFF + XT_BYTES)

typedef short    s16x8 __attribute__((ext_vector_type(8)));
typedef float    f32x4 __attribute__((ext_vector_type(4)));
typedef unsigned u32x4 __attribute__((ext_vector_type(4)));

__device__ __forceinline__ unsigned short f2bf(float f) {
  unsigned u = __builtin_bit_cast(unsigned, f);
  u += 0x7fffu + ((u >> 16) & 1u);               // RTNE
  return (unsigned short)(u >> 16);
}

// ---------------- batch fp32 -> bf16 prepass ----------------
__global__ void horn_convert(const float* __restrict__ src, unsigned short* __restrict__ dst) {
  size_t gid = (size_t)blockIdx.x * 256 + threadIdx.x;
  const f32x4* s4 = reinterpret_cast<const f32x4*>(src) + gid * 2;
  f32x4 a = s4[0], b = s4[1];
  u32x4 o;
  o[0] = (unsigned)f2bf(a[0]) | ((unsigned)f2bf(a[1]) << 16);
  o[1] = (unsigned)f2bf(a[2]) | ((unsigned)f2bf(a[3]) << 16);
  o[2] = (unsigned)f2bf(b[0]) | ((unsigned)f2bf(b[1]) << 16);
  o[3] = (unsigned)f2bf(b[2]) | ((unsigned)f2bf(b[3]) << 16);
  reinterpret_cast<u32x4*>(dst)[gid] = o;
}

// ---------------- persistent recurrent kernel ----------------
// LDS: ylds[4 waves][8KB private K-quarter tile] + red[2 parity][16][64] f32x4
__launch_bounds__(THREADS, 1)
__global__ void horn_persistent(const unsigned short* __restrict__ batchbf,
                                const float* __restrict__ i2h_w,
                                const float* __restrict__ i2h_b,
                                const float* __restrict__ h2h_w,
                                const float* __restrict__ h2h_b,
                                unsigned short* ybuf,     // bf16 [2][16][16][1024]
                                unsigned int*  flags,     // u32 [16][64]
                                float* xT)                // [256][1024] fp32
{
  __shared__ char  ylds[32768];                    // wave wv: [wv*8192, +8192)
  __shared__ f32x4 red[2][16][64];                 // [parity][wv*4+ct][lane]

  const int tid  = threadIdx.x;
  const int lane = tid & 63;
  const int wv   = tid >> 6;          // wave 0..3: K-quarter wv, owned ct = wv
  const int blk  = blockIdx.x;
  const int ig   = blk & 15;          // batch group (16 rows)
  const int jg   = blk >> 4;          // col-slice 0..15 (64 cols)
  const int l15  = lane & 15;
  const int kb   = lane >> 4;
  const int jc   = jg * 64 + wv * 16 + l15;        // owned output column

  // ---- W fragments: 4 ct x 8 kc (K-quarter wv), xGAIN = 128 VGPRs ----
  s16x8 wfrag[4][8];
  #pragma unroll
  for (int ct = 0; ct < 4; ++ct) {
    #pragma unroll
    for (int kc = 0; kc < 8; ++kc) {
      const float* gp = h2h_w + (size_t)(jg * 64 + ct * 16 + l15) * NDIM
                        + wv * 256 + kc * 32 + kb * 8;
      f32x4 a = *reinterpret_cast<const f32x4*>(gp);
      f32x4 b = *reinterpret_cast<const f32x4*>(gp + 4);
      s16x8 v;
      v[0] = (short)f2bf(a[0]*GAIN); v[1] = (short)f2bf(a[1]*GAIN);
      v[2] = (short)f2bf(a[2]*GAIN); v[3] = (short)f2bf(a[3]*GAIN);
      v[4] = (short)f2bf(b[0]*GAIN); v[5] = (short)f2bf(b[1]*GAIN);
      v[6] = (short)f2bf(b[2]*GAIN); v[7] = (short)f2bf(b[3]*GAIN);
      wfrag[ct][kc] = v;
    }
  }
  // ---- i2h B-frags + fused bias ----
  s16x8 i2hf[4];
  #pragma unroll
  for (int kc = 0; kc < 4; ++kc) {
    const float* gp = i2h_w + (size_t)jc * IDIM + kc * 32 + kb * 8;
    s16x8 v;
    #pragma unroll
    for (int e = 0; e < 8; ++e) v[e] = (short)f2bf(gp[e]);
    i2hf[kc] = v;
  }
  const float bias = i2h_b[jc] + GAIN * h2h_b[jc];

  // ---- per-lane pointers ----
  // private gather: load i covers rows {2i, 2i+1}; lane: row = 2i + (lane>>5),
  // byte-in-quarter = (lane&31)*16. addr = base + row*2048 + wv*512 + (lane&31)*16
  const char* gb0 = (const char*)ybuf + (size_t)ig * 32768
                    + (size_t)(lane >> 5) * 2048 + wv * 512 + (lane & 31) * 16;
  unsigned short* pub0 = ybuf + (size_t)(ig * 16 + kb * 4) * 1024 + jc;
  const unsigned* fpoll = flags + ig * 64 + lane;   // wv0 reads 64 flags
  unsigned* fstore = flags + ig * 64 + jg * 4 + wv; // per-wave flag
  const char* bb = (const char*)batchbf;
  const size_t boff_lane = (size_t)(ig * 16 + l15) * 256 + kb * 16;  // + t*65536

  float xs[4] = {0,0,0,0}, ys[4] = {0,0,0,0};
  u32x4 pf0, pf1, pf2, pf3;                        // batch prefetch regs
  u32x4 gy0, gy1, gy2, gy3, gy4, gy5, gy6, gy7;    // y gather regs

  #define PREFETCH(T) { const char* bp_ = bb + (size_t)(T) * 65536 + boff_lane; \
    asm volatile( \
      "global_load_dwordx4 %0, %4, off offset:0\n\t"  \
      "global_load_dwordx4 %1, %4, off offset:64\n\t" \
      "global_load_dwordx4 %2, %4, off offset:128\n\t"\
      "global_load_dwordx4 %3, %4, off offset:192"    \
      : "=&v"(pf0), "=&v"(pf1), "=&v"(pf2), "=&v"(pf3) : "v"(bp_) : "memory"); }

  #define UPHASE(uacc) { \
    uacc = __builtin_amdgcn_mfma_f32_16x16x32_bf16(__builtin_bit_cast(s16x8, pf0), i2hf[0], uacc, 0, 0, 0); \
    uacc = __builtin_amdgcn_mfma_f32_16x16x32_bf16(__builtin_bit_cast(s16x8, pf1), i2hf[1], uacc, 0, 0, 0); \
    uacc = __builtin_amdgcn_mfma_f32_16x16x32_bf16(__builtin_bit_cast(s16x8, pf2), i2hf[2], uacc, 0, 0, 0); \
    uacc = __builtin_amdgcn_mfma_f32_16x16x32_bf16(__builtin_bit_cast(s16x8, pf3), i2hf[3], uacc, 0, 0, 0); }

  #define UPD4(z) \
    unsigned yw0, yw1, yw2, yw3; { float z_, e_, th_, yn_; \
    z_ = z[0]; e_ = __expf(z_ + z_); th_ = fmaf(-2.0f, __builtin_amdgcn_rcpf(e_ + 1.0f), 1.0f); \
    yn_ = ys[0] + 0.1f*(th_ - xs[0] - 0.2f*ys[0]); xs[0] += 0.1f*yn_; ys[0] = yn_; yw0 = f2bf(yn_); \
    z_ = z[1]; e_ = __expf(z_ + z_); th_ = fmaf(-2.0f, __builtin_amdgcn_rcpf(e_ + 1.0f), 1.0f); \
    yn_ = ys[1] + 0.1f*(th_ - xs[1] - 0.2f*ys[1]); xs[1] += 0.1f*yn_; ys[1] = yn_; yw1 = f2bf(yn_); \
    z_ = z[2]; e_ = __expf(z_ + z_); th_ = fmaf(-2.0f, __builtin_amdgcn_rcpf(e_ + 1.0f), 1.0f); \
    yn_ = ys[2] + 0.1f*(th_ - xs[2] - 0.2f*ys[2]); xs[2] += 0.1f*yn_; ys[2] = yn_; yw2 = f2bf(yn_); \
    z_ = z[3]; e_ = __expf(z_ + z_); th_ = fmaf(-2.0f, __builtin_amdgcn_rcpf(e_ + 1.0f), 1.0f); \
    yn_ = ys[3] + 0.1f*(th_ - xs[3] - 0.2f*ys[3]); xs[3] += 0.1f*yn_; ys[3] = yn_; yw3 = f2bf(yn_); }

  #define PUBLISH(PN) { \
    unsigned short* b0_ = pub0 + (size_t)(PN) * YHALF_EL; \
    unsigned short* b1_ = b0_ + 2 * NDIM; \
    asm volatile( \
      "global_store_short %4, %0, off offset:0    sc0 sc1\n\t" \
      "global_store_short %4, %1, off offset:2048 sc0 sc1\n\t" \
      "global_store_short %5, %2, off offset:0    sc0 sc1\n\t" \
      "global_store_short %5, %3, off offset:2048 sc0 sc1" \
      :: "v"(yw0), "v"(yw1), "v"(yw2), "v"(yw3), "v"(b0_), "v"(b1_) : "memory"); }

  #define SETFLAG(V) { unsigned nv_ = (unsigned)(V); \
    asm volatile("global_store_dword %0, %1, off sc0 sc1" :: "v"(fstore), "v"(nv_) : "memory"); }

  // ---- prologue: step t=0 (y_0 = 0 -> u-phase only) ----
  PREFETCH(0)
  asm volatile("s_waitcnt vmcnt(0)" ::: "memory");
  __builtin_amdgcn_sched_barrier(0);
  {
    f32x4 uacc = {bias, bias, bias, bias};
    UPHASE(uacc)
    UPD4(uacc)
    PUBLISH(1)                                     // y_1 -> parity 1
    PREFETCH(1)
    asm volatile("s_waitcnt vmcnt(4)" ::: "memory");   // 4 oldest = the stores
    SETFLAG(1)
  }
  // in-flight now: 4 prefetch loads + 1 flag store (untracked by compiler)

  #pragma unroll 1
  for (int t = 1; t < T_STEPS; ++t) {
    const int p = t & 1, pn = p ^ 1;

    // ---- poll (wv0 only: ~256 concurrent pollers device-wide) ----
    if (wv == 0) {
      while (true) {
        unsigned fv;
        asm volatile("global_load_dword %0, %1, off sc0 sc1\n\ts_waitcnt vmcnt(0)"
                     : "=v"(fv) : "v"(fpoll) : "memory");
        if (__all((int)fv >= t)) break;
        __builtin_amdgcn_s_sleep(1);
      }
    }
    __syncthreads();                               // barP: release all waves

    // ---- issue own K-quarter gather (private; no cross-wave dependency) ----
    {
      const char* g0 = gb0 + (size_t)p * YBUF_HALF;
      asm volatile(
        "global_load_dwordx4 %0, %8, off sc0 sc1\n\t"
        "global_load_dwordx4 %1, %9, off sc0 sc1\n\t"
        "global_load_dwordx4 %2, %10, off sc0 sc1\n\t"
        "global_load_dwordx4 %3, %11, off sc0 sc1\n\t"
        "global_load_dwordx4 %4, %12, off sc0 sc1\n\t"
        "global_load_dwordx4 %5, %13, off sc0 sc1\n\t"
        "global_load_dwordx4 %6, %14, off sc0 sc1\n\t"
        "global_load_dwordx4 %7, %15, off sc0 sc1"
        : "=&v"(gy0), "=&v"(gy1), "=&v"(gy2), "=&v"(gy3),
          "=&v"(gy4), "=&v"(gy5), "=&v"(gy6), "=&v"(gy7)
        : "v"(g0), "v"(g0 + 4096), "v"(g0 + 8192), "v"(g0 + 12288),
          "v"(g0 + 16384), "v"(g0 + 20480), "v"(g0 + 24576), "v"(g0 + 28672)
        : "memory");
    }

    // ---- THE FIX: retire the 5 oldest (4 prefetch loads + flag store)
    //      before consuming pf; gather's 8 stay in flight ----
    asm volatile("s_waitcnt vmcnt(8)" ::: "memory");
    __builtin_amdgcn_sched_barrier(0);             // rule #18: pin MFMAs below

    // ---- u-phase under the gather shadow ----
    f32x4 uacc = {bias, bias, bias, bias};
    UPHASE(uacc)

    asm volatile("s_waitcnt vmcnt(0)" ::: "memory");   // own gather done
    __builtin_amdgcn_sched_barrier(0);

    // ---- stage to private LDS tile (512B rows, 4-bit XOR swizzle) ----
    {
      char* base = ylds + wv * 8192;
      int h = lane >> 5, c16 = (lane & 31) << 4;
      #define STG(i, vr) { int row_ = 2 * (i) + h; \
        *reinterpret_cast<u32x4*>(base + row_ * 512 + (c16 ^ ((row_ & 15) << 4))) = vr; }
      STG(0, gy0) STG(1, gy1) STG(2, gy2) STG(3, gy3)
      STG(4, gy4) STG(5, gy5) STG(6, gy6) STG(7, gy7)
      #undef STG
    }
    asm volatile("s_waitcnt lgkmcnt(0)" ::: "memory");
    __builtin_amdgcn_sched_barrier(0);

    // ---- rec partials from own tile: 4 ct x 8 kc MFMAs ----
    f32x4 c0 = {0,0,0,0}, c1 = {0,0,0,0}, c2 = {0,0,0,0}, c3 = {0,0,0,0};
    {
      const char* base = ylds + wv * 8192 + l15 * 512;
      const int swz = (l15 & 15) << 4;
      #pragma unroll
      for (int kc = 0; kc < 8; ++kc) {
        s16x8 a = *reinterpret_cast<const s16x8*>(base + ((kc * 64 + kb * 16) ^ swz));
        c0 = __builtin_amdgcn_mfma_f32_16x16x32_bf16(a, wfrag[0][kc], c0, 0, 0, 0);
        c1 = __builtin_amdgcn_mfma_f32_16x16x32_bf16(a, wfrag[1][kc], c1, 0, 0, 0);
        c2 = __builtin_amdgcn_mfma_f32_16x16x32_bf16(a, wfrag[2][kc], c2, 0, 0, 0);
        c3 = __builtin_amdgcn_mfma_f32_16x16x32_bf16(a, wfrag[3][kc], c3, 0, 0, 0);
      }
    }

    // ---- cross-wave K-reduction (parity double-buffered) ----
    red[p][wv * 4 + 0][lane] = c0;
    red[p][wv * 4 + 1][lane] = c1;
    red[p][wv * 4 + 2][lane] = c2;
    red[p][wv * 4 + 3][lane] = c3;
    __syncthreads();                               // bar2
    f32x4 z = uacc;
    z += red[p][0 * 4 + wv][lane];
    z += red[p][1 * 4 + wv][lane];
    z += red[p][2 * 4 + wv][lane];
    z += red[p][3 * 4 + wv][lane];

    // ---- update, publish, prefetch, counted drain (stores only), flag ----
    UPD4(z)
    PUBLISH(pn)
    const int tn = (t + 1 < T_STEPS) ? (t + 1) : t;
    PREFETCH(tn)
    asm volatile("s_waitcnt vmcnt(4)" ::: "memory");   // 4 oldest = y stores acked
    SETFLAG(t + 1)
  }

  #undef PREFETCH
  #undef UPHASE
  #undef UPD4
  #undef PUBLISH
  #undef SETFLAG

  asm volatile("s_waitcnt vmcnt(0)" ::: "memory");

  // ---- write x_T (owned column, 4 rows) ----
  #pragma unroll
  for (int q = 0; q < 4; ++q) {
    int row = ig * 16 + kb * 4 + q;
    xT[(size_t)row * NDIM + jc] = xs[q];
  }
}

// ---------------- final readout: out = x_T @ h2o^T + b ----------------
__global__ void horn_out(const float* __restrict__ xT, const float* __restrict__ h2o_w,
                         const float* __restrict__ h2o_b, float* __restrict__ out) {
  int b = blockIdx.x;
  int lane = threadIdx.x;                  // 64 threads
  float p[ODIM];
  #pragma unroll
  for (int o = 0; o < ODIM; ++o) p[o] = 0.f;
  for (int it = 0; it < NDIM / 64; ++it) {
    int n = it * 64 + lane;
    float xv = xT[(size_t)b * NDIM + n];
    #pragma unroll
    for (int o = 0; o < ODIM; ++o) p[o] += xv * h2o_w[o * NDIM + n];
  }
  #pragma unroll
  for (int o = 0; o < ODIM; ++o) {
    float v = p[o];
    #pragma unroll
    for (int off = 32; off >= 1; off >>= 1) v += __shfl_down(v, off, 64);
    if (lane == 0) out[b * ODIM + o] = v + h2o_b[o];
  }
}

__global__ void horn_fail(float* out) {    // loud sentinel if ws too small
  int i = blockIdx.x * 256 + threadIdx.x;
  if (i < BATCH_N * ODIM) out[i] = 12345.0f;
}

extern "C" void kernel_launch(void* const* d_in, const int* in_sizes, int n_in,
                              void* d_out, int out_size, void* d_ws, size_t ws_size,
                              hipStream_t stream) {
  const float* batch = (const float*)d_in[0];
  const float* i2h_w = (const float*)d_in[1];
  const float* i2h_b = (const float*)d_in[2];
  const float* h2h_w = (const float*)d_in[3];
  const float* h2h_b = (const float*)d_in[4];
  const float* h2o_w = (const float*)d_in[5];
  const float* h2o_b = (const float*)d_in[6];
  float* out = (float*)d_out;
  char* ws = (char*)d_ws;

  if (ws_size < WS_NEED) {
    horn_fail<<<16, 256, 0, stream>>>(out);
    return;
  }

  hipMemsetAsync(ws + FLG_OFF, 0, FLG_BYTES, stream);    // flags = 0

  horn_convert<<<8192, 256, 0, stream>>>(batch, (unsigned short*)(ws + 0));

  horn_persistent<<<256, THREADS, 0, stream>>>(
      (const unsigned short*)(ws + 0), i2h_w, i2h_b, h2h_w, h2h_b,
      (unsigned short*)(ws + YBUF_OFF), (unsigned int*)(ws + FLG_OFF),
      (float*)(ws + XT_OFF));

  horn_out<<<BATCH_N, 64, 0, stream>>>((const float*)(ws + XT_OFF), h2o_w, h2o_b, out);
}

// Round 17
// 2878.252 us; speedup vs baseline: 1.6133x; 1.1963x over previous
//
#include <hip/hip_runtime.h>

// ---------------- problem constants ----------------
#define T_STEPS 512
#define BATCH_N 256
#define IDIM    128
#define NDIM    1024
#define ODIM    10

// 256 WGs = 16 batch-groups (16 rows) x 16 col-slices (64 cols), 4 waves.
// R17 = R11 EXACTLY (cooperative coalesced gather -> swizzled LDS, reg-W,
// wv0-only poll + barrier release) with ONE change (A/B isolation):
//   per-wave flags [16][64], set after each wave's own counted vmcnt(4)
//   drain (publish stores acked), bar3 deleted.
// If this regresses like R16, the per-wave-flag scheme is R16's poison;
// if it holds ~R11, the private segmented gather was.
#define THREADS 256
#define GAIN 0.03125f

// ---------------- workspace layout (bytes) ----------------
#define YBUF_OFF    (33554432ull)                 // after bf16 batch [512][256][128]
#define YBUF_HALF   (524288ull)                   // bytes per parity: bf16 [16][16][1024]
#define YHALF_EL    (262144u)                     // ushort elements per parity
#define FLG_OFF     (YBUF_OFF + 2*YBUF_HALF)
#define FLG_BYTES   (4096ull)                     // u32 [16 groups][64 waves]
#define XT_OFF      (FLG_OFF + FLG_BYTES)
#define XT_BYTES    (1048576ull)                  // fp32 [256][1024]
#define WS_NEED     (XT_OFF + XT_BYTES)

typedef short    s16x8 __attribute__((ext_vector_type(8)));
typedef float    f32x4 __attribute__((ext_vector_type(4)));
typedef unsigned u32x4 __attribute__((ext_vector_type(4)));

__device__ __forceinline__ unsigned short f2bf(float f) {
  unsigned u = __builtin_bit_cast(unsigned, f);
  u += 0x7fffu + ((u >> 16) & 1u);               // RTNE
  return (unsigned short)(u >> 16);
}

// ---------------- batch fp32 -> bf16 prepass ----------------
__global__ void horn_convert(const float* __restrict__ src, unsigned short* __restrict__ dst) {
  size_t gid = (size_t)blockIdx.x * 256 + threadIdx.x;
  const f32x4* s4 = reinterpret_cast<const f32x4*>(src) + gid * 2;
  f32x4 a = s4[0], b = s4[1];
  u32x4 o;
  o[0] = (unsigned)f2bf(a[0]) | ((unsigned)f2bf(a[1]) << 16);
  o[1] = (unsigned)f2bf(a[2]) | ((unsigned)f2bf(a[3]) << 16);
  o[2] = (unsigned)f2bf(b[0]) | ((unsigned)f2bf(b[1]) << 16);
  o[3] = (unsigned)f2bf(b[2]) | ((unsigned)f2bf(b[3]) << 16);
  reinterpret_cast<u32x4*>(dst)[gid] = o;
}

// ---------------- persistent recurrent kernel ----------------
// LDS: y-stage bf16 [16 rows][1024], XOR-swizzled (32 KB) + red[4][4][64] f32x4 (16 KB)
__launch_bounds__(THREADS, 1)
__global__ void horn_persistent(const unsigned short* __restrict__ batchbf,
                                const float* __restrict__ i2h_w,
                                const float* __restrict__ i2h_b,
                                const float* __restrict__ h2h_w,
                                const float* __restrict__ h2h_b,
                                unsigned short* ybuf,     // bf16 [2][16][16][1024]
                                unsigned int*  flags,     // u32 [16][64]
                                float* xT)                // [256][1024] fp32
{
  __shared__ char  ylds[32768];
  __shared__ f32x4 red[4][4][64];                  // [ki][ct][lane]

  const int tid  = threadIdx.x;
  const int lane = tid & 63;
  const int wv   = tid >> 6;          // wave 0..3: K-quarter wv, owned ct = wv
  const int blk  = blockIdx.x;
  const int ig   = blk & 15;          // batch group (16 rows)
  const int jg   = blk >> 4;          // col-slice 0..15 (64 cols)
  const int l15  = lane & 15;
  const int kb   = lane >> 4;
  const int jc   = jg * 64 + wv * 16 + l15;        // owned output column

  // ---- W fragments: 4 ct x 8 kc (K-quarter wv), xGAIN = 128 VGPRs ----
  s16x8 wfrag[4][8];
  #pragma unroll
  for (int ct = 0; ct < 4; ++ct) {
    #pragma unroll
    for (int kc = 0; kc < 8; ++kc) {
      const float* gp = h2h_w + (size_t)(jg * 64 + ct * 16 + l15) * NDIM
                        + wv * 256 + kc * 32 + kb * 8;
      f32x4 a = *reinterpret_cast<const f32x4*>(gp);
      f32x4 b = *reinterpret_cast<const f32x4*>(gp + 4);
      s16x8 v;
      v[0] = (short)f2bf(a[0]*GAIN); v[1] = (short)f2bf(a[1]*GAIN);
      v[2] = (short)f2bf(a[2]*GAIN); v[3] = (short)f2bf(a[3]*GAIN);
      v[4] = (short)f2bf(b[0]*GAIN); v[5] = (short)f2bf(b[1]*GAIN);
      v[6] = (short)f2bf(b[2]*GAIN); v[7] = (short)f2bf(b[3]*GAIN);
      wfrag[ct][kc] = v;
    }
  }

  // ---- i2h B-frags for owned column + fused bias ----
  s16x8 i2hf[4];
  #pragma unroll
  for (int kc = 0; kc < 4; ++kc) {
    const float* gp = i2h_w + (size_t)jc * IDIM + kc * 32 + kb * 8;
    s16x8 v;
    #pragma unroll
    for (int e = 0; e < 8; ++e) v[e] = (short)f2bf(gp[e]);
    i2hf[kc] = v;
  }
  const float bias = i2h_b[jc] + GAIN * h2h_b[jc];

  // ---- batch A-frags for t=0 ----
  s16x8 bfr[4];
  {
    const unsigned short* bp = batchbf + ((size_t)ig * 16 + l15) * IDIM + kb * 8;
    #pragma unroll
    for (int kc = 0; kc < 4; ++kc) bfr[kc] = *reinterpret_cast<const s16x8*>(bp + kc * 32);
  }

  float xs[4] = {0.f,0.f,0.f,0.f};
  float ys[4] = {0.f,0.f,0.f,0.f};

  const char* ytile = (const char*)ybuf + (size_t)ig * 32768;            // + p*YBUF_HALF
  unsigned short* pub0 = ybuf + (size_t)(ig * 16 + kb * 4) * 1024 + jc;  // + pn*YHALF_EL
  const unsigned* fpoll = flags + ig * 64 + lane;                        // wv0 reads 64 flags
  unsigned* fstore = flags + ig * 64 + jg * 4 + wv;                      // per-wave flag

  for (int t = 0; t < T_STEPS; ++t) {
    const int p = t & 1, pn = p ^ 1;

    // ---- poll (wv0 only, plain coalesced load of the 64-flag region) ----
    if (t > 0) {
      if (wv == 0) {
        while (true) {
          unsigned fv;
          asm volatile("global_load_dword %0, %1, off sc0 sc1\n\t"
                       "s_waitcnt vmcnt(0)"
                       : "=v"(fv) : "v"(fpoll) : "memory");
          if (__all((int)fv >= t)) break;
          __builtin_amdgcn_s_sleep(1);
        }
      }
      __syncthreads();                             // barP: release all waves
    }

    // ---- coalesced gather of the 32KB y tile (16B/thread x 8 rounds) ----
    const char* q0 = ytile + (size_t)p * YBUF_HALF + tid * 16;
    u32x4 v0, v1, v2, v3, v4, v5, v6, v7;
    asm volatile(
      "global_load_dwordx4 %0, %8, off sc0 sc1\n\t"
      "global_load_dwordx4 %1, %9, off sc0 sc1\n\t"
      "global_load_dwordx4 %2, %10, off sc0 sc1\n\t"
      "global_load_dwordx4 %3, %11, off sc0 sc1\n\t"
      "global_load_dwordx4 %4, %12, off sc0 sc1\n\t"
      "global_load_dwordx4 %5, %13, off sc0 sc1\n\t"
      "global_load_dwordx4 %6, %14, off sc0 sc1\n\t"
      "global_load_dwordx4 %7, %15, off sc0 sc1"
      : "=&v"(v0), "=&v"(v1), "=&v"(v2), "=&v"(v3),
        "=&v"(v4), "=&v"(v5), "=&v"(v6), "=&v"(v7)
      : "v"(q0), "v"(q0 + 4096), "v"(q0 + 8192), "v"(q0 + 12288),
        "v"(q0 + 16384), "v"(q0 + 20480), "v"(q0 + 24576), "v"(q0 + 28672)
      : "memory");

    // ---- u-phase under the gather shadow ----
    f32x4 uacc = {bias, bias, bias, bias};
    #pragma unroll
    for (int kc = 0; kc < 4; ++kc)
      uacc = __builtin_amdgcn_mfma_f32_16x16x32_bf16(bfr[kc], i2hf[kc], uacc, 0, 0, 0);

    asm volatile("s_waitcnt vmcnt(0)" ::: "memory");
    __builtin_amdgcn_sched_barrier(0);             // rule #18

    // ---- stage to LDS, XOR-swizzled ----
    #define STG(r, vr) { int B_ = (r) * 4096 + tid * 16; int row_ = B_ >> 11; \
      *reinterpret_cast<u32x4*>(ylds + (B_ ^ ((row_ & 7) << 4))) = vr; }
    STG(0, v0) STG(1, v1) STG(2, v2) STG(3, v3)
    STG(4, v4) STG(5, v5) STG(6, v6) STG(7, v7)
    #undef STG
    __syncthreads();                               // bar1: tile ready

    // ---- rec partials: 4 ct x 8 kc MFMAs, A-frags from LDS ----
    f32x4 c0 = {0,0,0,0}, c1 = {0,0,0,0}, c2 = {0,0,0,0}, c3 = {0,0,0,0};
    #pragma unroll
    for (int kc = 0; kc < 8; ++kc) {
      int boff = (l15 * 2048 + wv * 512 + kc * 64 + kb * 16) ^ ((l15 & 7) << 4);
      s16x8 a = *reinterpret_cast<const s16x8*>(ylds + boff);
      c0 = __builtin_amdgcn_mfma_f32_16x16x32_bf16(a, wfrag[0][kc], c0, 0, 0, 0);
      c1 = __builtin_amdgcn_mfma_f32_16x16x32_bf16(a, wfrag[1][kc], c1, 0, 0, 0);
      c2 = __builtin_amdgcn_mfma_f32_16x16x32_bf16(a, wfrag[2][kc], c2, 0, 0, 0);
      c3 = __builtin_amdgcn_mfma_f32_16x16x32_bf16(a, wfrag[3][kc], c3, 0, 0, 0);
    }

    // ---- cross-wave K-reduction (single buffer; fenced by barP+bar1) ----
    red[wv][0][lane] = c0;
    red[wv][1][lane] = c1;
    red[wv][2][lane] = c2;
    red[wv][3][lane] = c3;
    __syncthreads();                               // bar2: partials ready
    f32x4 z = uacc;
    z += red[0][wv][lane];
    z += red[1][wv][lane];
    z += red[2][wv][lane];
    z += red[3][wv][lane];

    // ---- state update (fp32, fast tanh) ----
    unsigned yw0, yw1, yw2, yw3;
    {
      float zz, e, r, th, yn;
      zz = z[0]; e = __expf(zz + zz); r = __builtin_amdgcn_rcpf(e + 1.0f); th = fmaf(-2.0f, r, 1.0f);
      yn = ys[0] + 0.1f*(th - xs[0] - 0.2f*ys[0]); xs[0] += 0.1f*yn; ys[0] = yn; yw0 = f2bf(yn);
      zz = z[1]; e = __expf(zz + zz); r = __builtin_amdgcn_rcpf(e + 1.0f); th = fmaf(-2.0f, r, 1.0f);
      yn = ys[1] + 0.1f*(th - xs[1] - 0.2f*ys[1]); xs[1] += 0.1f*yn; ys[1] = yn; yw1 = f2bf(yn);
      zz = z[2]; e = __expf(zz + zz); r = __builtin_amdgcn_rcpf(e + 1.0f); th = fmaf(-2.0f, r, 1.0f);
      yn = ys[2] + 0.1f*(th - xs[2] - 0.2f*ys[2]); xs[2] += 0.1f*yn; ys[2] = yn; yw2 = f2bf(yn);
      zz = z[3]; e = __expf(zz + zz); r = __builtin_amdgcn_rcpf(e + 1.0f); th = fmaf(-2.0f, r, 1.0f);
      yn = ys[3] + 0.1f*(th - xs[3] - 0.2f*ys[3]); xs[3] += 0.1f*yn; ys[3] = yn; yw3 = f2bf(yn);
    }

    // ---- publish y_{t+1}; prefetch; counted drain (stores only); flag ----
    {
      unsigned short* b0 = pub0 + (size_t)pn * YHALF_EL;
      unsigned short* b1 = b0 + 2 * NDIM;
      asm volatile(
        "global_store_short %4, %0, off offset:0    sc0 sc1\n\t"
        "global_store_short %4, %1, off offset:2048 sc0 sc1\n\t"
        "global_store_short %5, %2, off offset:0    sc0 sc1\n\t"
        "global_store_short %5, %3, off offset:2048 sc0 sc1"
        :
        : "v"(yw0), "v"(yw1), "v"(yw2), "v"(yw3), "v"(b0), "v"(b1)
        : "memory");
    }
    {
      const int tn = (t + 1 < T_STEPS) ? (t + 1) : t;
      const unsigned short* bp = batchbf + ((size_t)tn * BATCH_N + ig * 16 + l15) * IDIM + kb * 8;
      #pragma unroll
      for (int kc = 0; kc < 4; ++kc) bfr[kc] = *reinterpret_cast<const s16x8*>(bp + kc * 32);
    }
    asm volatile("s_waitcnt vmcnt(4)" ::: "memory");   // 4 oldest = y stores acked
    if (lane == 0) {
      unsigned nv = (unsigned)(t + 1);
      asm volatile("global_store_dword %0, %1, off sc0 sc1"
                   :: "v"(fstore), "v"(nv) : "memory");
    }
    // (no bar3 — red reuse fenced by barP+bar1; compiler drains its own
    //  prefetch loads before their u-phase use / before barP's s_barrier)
  }

  // ---- write x_T (owned column, 4 rows) ----
  #pragma unroll
  for (int q = 0; q < 4; ++q) {
    int row = ig * 16 + kb * 4 + q;
    xT[(size_t)row * NDIM + jc] = xs[q];
  }
}

// ---------------- final readout: out = x_T @ h2o^T + b ----------------
__global__ void horn_out(const float* __restrict__ xT, const float* __restrict__ h2o_w,
                         const float* __restrict__ h2o_b, float* __restrict__ out) {
  int b = blockIdx.x;
  int lane = threadIdx.x;                  // 64 threads
  float p[ODIM];
  #pragma unroll
  for (int o = 0; o < ODIM; ++o) p[o] = 0.f;
  for (int it = 0; it < NDIM / 64; ++it) {
    int n = it * 64 + lane;
    float xv = xT[(size_t)b * NDIM + n];
    #pragma unroll
    for (int o = 0; o < ODIM; ++o) p[o] += xv * h2o_w[o * NDIM + n];
  }
  #pragma unroll
  for (int o = 0; o < ODIM; ++o) {
    float v = p[o];
    #pragma unroll
    for (int off = 32; off >= 1; off >>= 1) v += __shfl_down(v, off, 64);
    if (lane == 0) out[b * ODIM + o] = v + h2o_b[o];
  }
}

__global__ void horn_fail(float* out) {    // loud sentinel if ws too small
  int i = blockIdx.x * 256 + threadIdx.x;
  if (i < BATCH_N * ODIM) out[i] = 12345.0f;
}

extern "C" void kernel_launch(void* const* d_in, const int* in_sizes, int n_in,
                              void* d_out, int out_size, void* d_ws, size_t ws_size,
                              hipStream_t stream) {
  const float* batch = (const float*)d_in[0];
  const float* i2h_w = (const float*)d_in[1];
  const float* i2h_b = (const float*)d_in[2];
  const float* h2h_w = (const float*)d_in[3];
  const float* h2h_b = (const float*)d_in[4];
  const float* h2o_w = (const float*)d_in[5];
  const float* h2o_b = (const float*)d_in[6];
  float* out = (float*)d_out;
  char* ws = (char*)d_ws;

  if (ws_size < WS_NEED) {
    horn_fail<<<16, 256, 0, stream>>>(out);
    return;
  }

  hipMemsetAsync(ws + YBUF_OFF, 0, YBUF_HALF, stream);   // y_0 = 0 (parity 0)
  hipMemsetAsync(ws + FLG_OFF, 0, FLG_BYTES, stream);    // flags = 0

  horn_convert<<<8192, 256, 0, stream>>>(batch, (unsigned short*)(ws + 0));

  horn_persistent<<<256, THREADS, 0, stream>>>(
      (const unsigned short*)(ws + 0), i2h_w, i2h_b, h2h_w, h2h_b,
      (unsigned short*)(ws + YBUF_OFF), (unsigned int*)(ws + FLG_OFF),
      (float*)(ws + XT_OFF));

  horn_out<<<BATCH_N, 64, 0, stream>>>((const float*)(ws + XT_OFF), h2o_w, h2o_b, out);
}

// Round 18
// 1883.756 us; speedup vs baseline: 2.4651x; 1.5279x over previous
//
#include <hip/hip_runtime.h>

// ---------------- problem constants ----------------
#define T_STEPS 512
#define BATCH_N 256
#define IDIM    128
#define NDIM    1024
#define ODIM    10

// R18 = R9 (128 WGs = 16 groups x 8 slices of 128 cols, 512 thr / 8 waves,
// W in regs, cooperative coalesced gather -> swizzled LDS) with R9's ONE
// poison fixed: poll is wv0-ONLY + barrier release (R14 proved all-wave
// device-scope polling collapses the fabric). Protocol = R11's proven
// skeleton: publish, vmcnt(0) drain, bar3, single per-WG flag, 1-line poll.
#define THREADS 512
#define GAIN 0.03125f

// ---------------- workspace layout (bytes) ----------------
#define YBUF_OFF    (33554432ull)                 // bf16 y [2][16][16][1024]
#define YBUF_HALF   (524288ull)                   // bytes per parity
#define YHALF_EL    (262144u)                     // ushort elements per parity
#define FLG_OFF     (YBUF_OFF + 2*YBUF_HALF)
#define FLG_BYTES   (1024ull)                     // u32 [16 groups][16 pad] (8 used)
#define XT_OFF      (FLG_OFF + FLG_BYTES)
#define XT_BYTES    (1048576ull)                  // fp32 [256][1024]
#define WS_NEED     (XT_OFF + XT_BYTES)

typedef short    s16x8 __attribute__((ext_vector_type(8)));
typedef float    f32x4 __attribute__((ext_vector_type(4)));
typedef unsigned u32x4 __attribute__((ext_vector_type(4)));

__device__ __forceinline__ unsigned short f2bf(float f) {
  unsigned u = __builtin_bit_cast(unsigned, f);
  u += 0x7fffu + ((u >> 16) & 1u);               // RTNE
  return (unsigned short)(u >> 16);
}

// ---------------- batch fp32 -> bf16 prepass ----------------
__global__ void horn_convert(const float* __restrict__ src, unsigned short* __restrict__ dst) {
  size_t gid = (size_t)blockIdx.x * 256 + threadIdx.x;
  const f32x4* s4 = reinterpret_cast<const f32x4*>(src) + gid * 2;
  f32x4 a = s4[0], b = s4[1];
  u32x4 o;
  o[0] = (unsigned)f2bf(a[0]) | ((unsigned)f2bf(a[1]) << 16);
  o[1] = (unsigned)f2bf(a[2]) | ((unsigned)f2bf(a[3]) << 16);
  o[2] = (unsigned)f2bf(b[0]) | ((unsigned)f2bf(b[1]) << 16);
  o[3] = (unsigned)f2bf(b[2]) | ((unsigned)f2bf(b[3]) << 16);
  reinterpret_cast<u32x4*>(dst)[gid] = o;
}

// ---------------- persistent recurrent kernel ----------------
// LDS: [0,32768)   y-stage bf16 [16 rows][1024], XOR-swizzled
//      [32768,65536) red[4 ki][8 ct][64 lane] f32x4
__launch_bounds__(THREADS, 2)
__global__ void horn_persistent(const unsigned short* __restrict__ batchbf,
                                const float* __restrict__ i2h_w,
                                const float* __restrict__ i2h_b,
                                const float* __restrict__ h2h_w,
                                const float* __restrict__ h2h_b,
                                unsigned short* ybuf,     // bf16 [2][16][16][1024]
                                unsigned int*  flags,     // u32 [16][16] (8 used/group)
                                float* xT)                // [256][1024] fp32
{
  extern __shared__ char smem[];
  char*  ylds = smem;                              // 32 KB
  f32x4* red  = (f32x4*)(smem + 32768);            // 32 KB

  const int tid  = threadIdx.x;
  const int lane = tid & 63;
  const int wv   = tid >> 6;           // 0..7
  const int ki   = wv & 3;             // K-quarter [ki*256, ki*256+256)
  const int ci   = wv >> 2;            // ct-group: cts [ci*4, ci*4+4)
  const int g    = blockIdx.x & 15;    // batch group (16 rows)
  const int s    = blockIdx.x >> 4;    // col-slice 0..7 (128 cols)
  const int l15  = lane & 15;
  const int kb   = lane >> 4;
  const int ct_own = ci * 4 + ki;      // this wave's owned ct (bijective over 8)
  const int jc   = s * 128 + ct_own * 16 + l15;    // owned output column

  // ---- W fragments: 4 ct (ci-group) x 8 kc (K-quarter ki), xGAIN = 128 VGPRs ----
  s16x8 wfrag[4][8];
  #pragma unroll
  for (int j = 0; j < 4; ++j) {
    #pragma unroll
    for (int kc = 0; kc < 8; ++kc) {
      const float* gp = h2h_w + (size_t)(s * 128 + (ci * 4 + j) * 16 + l15) * NDIM
                        + ki * 256 + kc * 32 + kb * 8;
      f32x4 a = *reinterpret_cast<const f32x4*>(gp);
      f32x4 b = *reinterpret_cast<const f32x4*>(gp + 4);
      s16x8 v;
      v[0] = (short)f2bf(a[0]*GAIN); v[1] = (short)f2bf(a[1]*GAIN);
      v[2] = (short)f2bf(a[2]*GAIN); v[3] = (short)f2bf(a[3]*GAIN);
      v[4] = (short)f2bf(b[0]*GAIN); v[5] = (short)f2bf(b[1]*GAIN);
      v[6] = (short)f2bf(b[2]*GAIN); v[7] = (short)f2bf(b[3]*GAIN);
      wfrag[j][kc] = v;
    }
  }

  // ---- i2h B-frags for owned column + fused bias ----
  s16x8 i2hf[4];
  #pragma unroll
  for (int kc = 0; kc < 4; ++kc) {
    const float* gp = i2h_w + (size_t)jc * IDIM + kc * 32 + kb * 8;
    s16x8 v;
    #pragma unroll
    for (int e = 0; e < 8; ++e) v[e] = (short)f2bf(gp[e]);
    i2hf[kc] = v;
  }
  const float bias = i2h_b[jc] + GAIN * h2h_b[jc];

  // ---- batch A-frags for t=0 ----
  s16x8 bfr[4];
  {
    const unsigned short* bp = batchbf + ((size_t)g * 16 + l15) * IDIM + kb * 8;
    #pragma unroll
    for (int kc = 0; kc < 4; ++kc) bfr[kc] = *reinterpret_cast<const s16x8*>(bp + kc * 32);
  }

  float xs[4] = {0.f,0.f,0.f,0.f};
  float ys[4] = {0.f,0.f,0.f,0.f};

  const char* ytile = (const char*)ybuf + (size_t)g * 32768;            // + p*YBUF_HALF
  unsigned short* pub0 = ybuf + (size_t)(g * 16 + kb * 4) * 1024 + jc;  // + pn*YHALF_EL
  const unsigned* fpoll = flags + g * 16 + (lane & 7);                  // one 32B region
  unsigned* fstore = flags + g * 16 + s;

  for (int t = 0; t < T_STEPS; ++t) {
    const int p = t & 1, pn = p ^ 1;

    // ---- poll (wv0 ONLY: 128 concurrent pollers device-wide), then release ----
    if (t > 0) {
      if (wv == 0) {
        while (true) {
          unsigned fv;
          asm volatile("global_load_dword %0, %1, off sc0 sc1\n\t"
                       "s_waitcnt vmcnt(0)"
                       : "=v"(fv) : "v"(fpoll) : "memory");
          if (__all((int)fv >= t)) break;
          __builtin_amdgcn_s_sleep(1);
        }
      }
      __syncthreads();                             // barP: release all 8 waves
    }

    // ---- issue COALESCED gather of the 32KB y tile (16B/thread x 4 rounds) ----
    const char* q0 = ytile + (size_t)p * YBUF_HALF + tid * 16;
    u32x4 v0, v1, v2, v3;
    asm volatile(
      "global_load_dwordx4 %0, %4, off sc0 sc1\n\t"
      "global_load_dwordx4 %1, %5, off sc0 sc1\n\t"
      "global_load_dwordx4 %2, %6, off sc0 sc1\n\t"
      "global_load_dwordx4 %3, %7, off sc0 sc1"
      : "=&v"(v0), "=&v"(v1), "=&v"(v2), "=&v"(v3)
      : "v"(q0), "v"(q0 + 8192), "v"(q0 + 16384), "v"(q0 + 24576)
      : "memory");

    // ---- u-phase under the gather shadow: uacc = bias + batch_t @ i2h^T ----
    f32x4 uacc = {bias, bias, bias, bias};
    #pragma unroll
    for (int kc = 0; kc < 4; ++kc)
      uacc = __builtin_amdgcn_mfma_f32_16x16x32_bf16(bfr[kc], i2hf[kc], uacc, 0, 0, 0);

    // ---- prefetch batch for t+1 (absorbed by the same vmcnt) ----
    {
      const int tn = (t + 1 < T_STEPS) ? (t + 1) : t;
      const unsigned short* bp = batchbf + ((size_t)tn * BATCH_N + g * 16 + l15) * IDIM + kb * 8;
      #pragma unroll
      for (int kc = 0; kc < 4; ++kc) bfr[kc] = *reinterpret_cast<const s16x8*>(bp + kc * 32);
    }

    asm volatile("s_waitcnt vmcnt(0)" ::: "memory");
    __builtin_amdgcn_sched_barrier(0);             // rule #18

    // ---- stage to LDS, XOR-swizzled; lane-contiguous 16B ----
    #define STG(r, vr) { int off = tid * 16 + (r) * 8192; int row = off >> 11; \
      *reinterpret_cast<u32x4*>(ylds + (off ^ ((row & 7) << 4))) = vr; }
    STG(0, v0) STG(1, v1) STG(2, v2) STG(3, v3)
    #undef STG
    __syncthreads();                               // bar1: tile ready

    // ---- rec partials: 4 ct x 8 kc MFMAs, A-frags from LDS (1 read / kc) ----
    f32x4 c0 = {0,0,0,0}, c1 = {0,0,0,0}, c2 = {0,0,0,0}, c3 = {0,0,0,0};
    #pragma unroll
    for (int kc = 0; kc < 8; ++kc) {
      int boff = (l15 * 2048 + ki * 512 + kc * 64 + kb * 16) ^ ((l15 & 7) << 4);
      s16x8 a = *reinterpret_cast<const s16x8*>(ylds + boff);
      c0 = __builtin_amdgcn_mfma_f32_16x16x32_bf16(a, wfrag[0][kc], c0, 0, 0, 0);
      c1 = __builtin_amdgcn_mfma_f32_16x16x32_bf16(a, wfrag[1][kc], c1, 0, 0, 0);
      c2 = __builtin_amdgcn_mfma_f32_16x16x32_bf16(a, wfrag[2][kc], c2, 0, 0, 0);
      c3 = __builtin_amdgcn_mfma_f32_16x16x32_bf16(a, wfrag[3][kc], c3, 0, 0, 0);
    }

    // ---- cross-wave K-reduction (4 partials per output) ----
    red[((size_t)ki * 8 + ci * 4 + 0) * 64 + lane] = c0;
    red[((size_t)ki * 8 + ci * 4 + 1) * 64 + lane] = c1;
    red[((size_t)ki * 8 + ci * 4 + 2) * 64 + lane] = c2;
    red[((size_t)ki * 8 + ci * 4 + 3) * 64 + lane] = c3;
    __syncthreads();                               // bar2: partials ready
    f32x4 z = uacc;
    z += red[(0 * 8 + ct_own) * 64 + lane];
    z += red[(1 * 8 + ct_own) * 64 + lane];
    z += red[(2 * 8 + ct_own) * 64 + lane];
    z += red[(3 * 8 + ct_own) * 64 + lane];

    // ---- state update (fp32, fast tanh) ----
    unsigned yw0, yw1, yw2, yw3;
    {
      float zz, e, r, th, yn;
      zz = z[0]; e = __expf(zz + zz); r = __builtin_amdgcn_rcpf(e + 1.0f); th = fmaf(-2.0f, r, 1.0f);
      yn = ys[0] + 0.1f*(th - xs[0] - 0.2f*ys[0]); xs[0] += 0.1f*yn; ys[0] = yn; yw0 = f2bf(yn);
      zz = z[1]; e = __expf(zz + zz); r = __builtin_amdgcn_rcpf(e + 1.0f); th = fmaf(-2.0f, r, 1.0f);
      yn = ys[1] + 0.1f*(th - xs[1] - 0.2f*ys[1]); xs[1] += 0.1f*yn; ys[1] = yn; yw1 = f2bf(yn);
      zz = z[2]; e = __expf(zz + zz); r = __builtin_amdgcn_rcpf(e + 1.0f); th = fmaf(-2.0f, r, 1.0f);
      yn = ys[2] + 0.1f*(th - xs[2] - 0.2f*ys[2]); xs[2] += 0.1f*yn; ys[2] = yn; yw2 = f2bf(yn);
      zz = z[3]; e = __expf(zz + zz); r = __builtin_amdgcn_rcpf(e + 1.0f); th = fmaf(-2.0f, r, 1.0f);
      yn = ys[3] + 0.1f*(th - xs[3] - 0.2f*ys[3]); xs[3] += 0.1f*yn; ys[3] = yn; yw3 = f2bf(yn);
    }

    // ---- publish y_{t+1} (owned col, 4 rows), drain, WG-sync, single flag ----
    {
      unsigned short* b0 = pub0 + (size_t)pn * YHALF_EL;
      unsigned short* b1 = b0 + 2 * NDIM;
      asm volatile(
        "global_store_short %4, %0, off offset:0    sc0 sc1\n\t"
        "global_store_short %4, %1, off offset:2048 sc0 sc1\n\t"
        "global_store_short %5, %2, off offset:0    sc0 sc1\n\t"
        "global_store_short %5, %3, off offset:2048 sc0 sc1\n\t"
        "s_waitcnt vmcnt(0)"
        :
        : "v"(yw0), "v"(yw1), "v"(yw2), "v"(yw3), "v"(b0), "v"(b1)
        : "memory");
    }
    __syncthreads();                               // bar3: all waves drained
    if (tid == 0) {
      unsigned nv = (unsigned)(t + 1);
      asm volatile("global_store_dword %0, %1, off sc0 sc1"
                   :: "v"(fstore), "v"(nv) : "memory");
    }
  }

  // ---- write x_T (owned column, 4 rows) ----
  #pragma unroll
  for (int q = 0; q < 4; ++q) {
    int row = g * 16 + kb * 4 + q;
    xT[(size_t)row * NDIM + jc] = xs[q];
  }
}

// ---------------- final readout: out = x_T @ h2o^T + b ----------------
__global__ void horn_out(const float* __restrict__ xT, const float* __restrict__ h2o_w,
                         const float* __restrict__ h2o_b, float* __restrict__ out) {
  int b = blockIdx.x;
  int lane = threadIdx.x;                  // 64 threads
  float p[ODIM];
  #pragma unroll
  for (int o = 0; o < ODIM; ++o) p[o] = 0.f;
  for (int it = 0; it < NDIM / 64; ++it) {
    int n = it * 64 + lane;
    float xv = xT[(size_t)b * NDIM + n];
    #pragma unroll
    for (int o = 0; o < ODIM; ++o) p[o] += xv * h2o_w[o * NDIM + n];
  }
  #pragma unroll
  for (int o = 0; o < ODIM; ++o) {
    float v = p[o];
    #pragma unroll
    for (int off = 32; off >= 1; off >>= 1) v += __shfl_down(v, off, 64);
    if (lane == 0) out[b * ODIM + o] = v + h2o_b[o];
  }
}

__global__ void horn_fail(float* out) {    // loud sentinel if ws too small
  int i = blockIdx.x * 256 + threadIdx.x;
  if (i < BATCH_N * ODIM) out[i] = 12345.0f;
}

extern "C" void kernel_launch(void* const* d_in, const int* in_sizes, int n_in,
                              void* d_out, int out_size, void* d_ws, size_t ws_size,
                              hipStream_t stream) {
  const float* batch = (const float*)d_in[0];
  const float* i2h_w = (const float*)d_in[1];
  const float* i2h_b = (const float*)d_in[2];
  const float* h2h_w = (const float*)d_in[3];
  const float* h2h_b = (const float*)d_in[4];
  const float* h2o_w = (const float*)d_in[5];
  const float* h2o_b = (const float*)d_in[6];
  float* out = (float*)d_out;
  char* ws = (char*)d_ws;

  if (ws_size < WS_NEED) {
    horn_fail<<<16, 256, 0, stream>>>(out);
    return;
  }

  (void)hipFuncSetAttribute(reinterpret_cast<const void*>(horn_persistent),
                            hipFuncAttributeMaxDynamicSharedMemorySize, 65536);

  hipMemsetAsync(ws + YBUF_OFF, 0, YBUF_HALF, stream);   // y_0 = 0 (parity 0)
  hipMemsetAsync(ws + FLG_OFF, 0, FLG_BYTES, stream);    // flags = 0

  horn_convert<<<8192, 256, 0, stream>>>(batch, (unsigned short*)(ws + 0));

  horn_persistent<<<128, THREADS, 65536, stream>>>(
      (const unsigned short*)(ws + 0), i2h_w, i2h_b, h2h_w, h2h_b,
      (unsigned short*)(ws + YBUF_OFF), (unsigned int*)(ws + FLG_OFF),
      (float*)(ws + XT_OFF));

  horn_out<<<BATCH_N, 64, 0, stream>>>((const float*)(ws + XT_OFF), h2o_w, h2o_b, out);
}